// Round 3
// baseline (561.115 us; speedup 1.0000x reference)
//
#include <hip/hip_runtime.h>
#include <stdint.h>

typedef __attribute__((ext_vector_type(8))) short short8;
typedef __attribute__((ext_vector_type(8))) unsigned short ushort8;
typedef __attribute__((ext_vector_type(4))) float floatx4;

#define W_DIM 900
#define NPAD  450
#define NT    32           // K tiles: 1024 / BK, BK = 32
#define BUFB  16384        // bytes per LDS staging buffer (A 8 KB + B 8 KB)

// round-half-up fp32 -> bf16 (bias ~2^-17 relative; fine over ~1M-term sums)
__device__ __forceinline__ unsigned short f2bf(float f) {
  unsigned int u = __builtin_bit_cast(unsigned int, f);
  return (unsigned short)((u + 0x8000u) >> 16);
}

__device__ __forceinline__ ushort8 pk8(float4 a, float4 b) {
  ushort8 o;
  o[0] = f2bf(a.x); o[1] = f2bf(a.y); o[2] = f2bf(a.z); o[3] = f2bf(a.w);
  o[4] = f2bf(b.x); o[5] = f2bf(b.y); o[6] = f2bf(b.z); o[7] = f2bf(b.w);
  return o;
}

// Raw barrier: drain LDS ops only; global loads stay in flight across it
// (__syncthreads would emit vmcnt(0) and kill the prefetch).
#define BARRIER() do { asm volatile("s_waitcnt lgkmcnt(0)" ::: "memory"); \
                       __builtin_amdgcn_s_barrier(); } while (0)

// ---------------------------------------------------------------------------
// out[b,s] = sum_{i-j-450 = s (mod 900)} <x1_i, x2_j>, D = H*C = 1024.
//
// Round-3 design: occupancy first. acc[4][4] = 64 regs (was 128 -> 240 total
// -> 2 waves/SIMD cap, the r0-r2 limiter). Target <=170 total -> 3 waves/SIMD.
// Tile 128x128, 4 waves (2x2), wave = 64x64 via 4x4 frags of 16x16x32 bf16.
// Grid 1024 = 64 tiles * 16 b, x = t64*16 + b so x%8 = b%8 (XCD batch pair).
//
// LDS: identity-slot layout, zero bank conflicts. Per buffer: A image 8 KB
// (8 subtiles of 16 rows x 32 k bf16 = 1024 B), B image 8 KB. Chunk
// (r16 = row&15, k8 = k>>3) lives at byte slot (k8*16 + r16)*16 == lane*16,
// so ds_write_b128 (stage) and ds_read_b128 (frags) are both base + lane*16.
//
// Pipeline: 2 LDS buffers, ONE raw barrier per k-tile:
//   iter t: BARRIER (tile-t stores visible; tile t-1 frag reads drained)
//           CVTSTORE(t+1) [vmcnt-waits loads(t+1)]; LOADS(t+2); MFMA(tile t).
// WAR on buf[(t+1)&1]: its readers ran in iter t-1 and were lgkm-drained at
// this iter's barrier. RAW on buf[t&1]: written iter t-1, drained same way.
// ---------------------------------------------------------------------------
__global__ __launch_bounds__(256, 3)
void fused_gram_band(const float* __restrict__ X1, const float* __restrict__ X2,
                     float* __restrict__ out) {
  const int x   = blockIdx.x;
  const int b   = x & 15;
  const int t64 = x >> 4;
  const int it  = t64 >> 3;          // A tile: rows it*128..
  const int jt  = t64 & 7;           // B tile: rows jt*128..

  // staging 2*16384 = 32768 B; epilogue Ep[64][132]*4 = 33792 B aliases it
  __shared__ __align__(16) unsigned char smem[33792];

  const int tid  = threadIdx.x;
  const int lane = tid & 63;
  const int warp = tid >> 6;         // 0..3
  const int wm   = warp >> 1;
  const int wn   = warp & 1;
  const int r16  = lane & 15;
  const int quad = lane >> 4;

  // ---- staging rows: warp stages subtiles {warp, warp+4} of A and of B;
  // within a subtile, thread owns chunk (row r16, k-chunk quad) == slot lane.
  const int rA0 = it * 128 + warp * 16 + r16;
  const int rA1 = rA0 + 64;
  const int rB0 = jt * 128 + warp * 16 + r16;
  const int rB1 = rB0 + 64;
  const bool okA0 = rA0 < W_DIM, okA1 = rA1 < W_DIM;
  const bool okB0 = rB0 < W_DIM, okB1 = rB1 < W_DIM;

  const size_t bbase = (size_t)b * 4 * W_DIM * 256;
  const float* pA0 = X1 + bbase + (size_t)rA0 * 256 + quad * 8;
  const float* pA1 = X1 + bbase + (size_t)rA1 * 256 + quad * 8;
  const float* pB0 = X2 + bbase + (size_t)rB0 * 256 + quad * 8;
  const float* pB1 = X2 + bbase + (size_t)rB1 * 256 + quad * 8;

  const float4 fz = make_float4(0.f, 0.f, 0.f, 0.f);
  float4 va0, va1, va2, va3, vb0, vb1, vb2, vb3;

  // k-global = kt*32 + quad*8 + j -> h = kt>>3, c = (kt&7)*32 + quad*8 + j
#define LOADS(kt_)                                                            \
  { const size_t ko = (size_t)((kt_) >> 3) * (W_DIM * 256) +                  \
                      (size_t)(((kt_) & 7) * 32);                             \
    va0 = okA0 ? *(const float4*)(pA0 + ko)     : fz;                         \
    va1 = okA0 ? *(const float4*)(pA0 + ko + 4) : fz;                         \
    va2 = okA1 ? *(const float4*)(pA1 + ko)     : fz;                         \
    va3 = okA1 ? *(const float4*)(pA1 + ko + 4) : fz;                         \
    vb0 = okB0 ? *(const float4*)(pB0 + ko)     : fz;                         \
    vb1 = okB0 ? *(const float4*)(pB0 + ko + 4) : fz;                         \
    vb2 = okB1 ? *(const float4*)(pB1 + ko)     : fz;                         \
    vb3 = okB1 ? *(const float4*)(pB1 + ko + 4) : fz;                         \
  }

  // A image at buf+0, B image at buf+8192; subtile s at s*1024; slot = lane.
#define CVTSTORE(wr_)                                                         \
  { unsigned char* wb = smem + (wr_) * BUFB + warp * 1024 + (lane << 4);      \
    *(ushort8*)(wb)          = pk8(va0, va1);   /* A subtile warp   */        \
    *(ushort8*)(wb + 4096)   = pk8(va2, va3);   /* A subtile warp+4 */        \
    *(ushort8*)(wb + 8192)   = pk8(vb0, vb1);   /* B subtile warp   */        \
    *(ushort8*)(wb + 12288)  = pk8(vb2, vb3);   /* B subtile warp+4 */        \
  }

  floatx4 acc[4][4];
#pragma unroll
  for (int i = 0; i < 4; ++i)
#pragma unroll
    for (int j = 0; j < 4; ++j) acc[i][j] = (floatx4)0.0f;

  // frag read bases (identity slots, conflict-free):
  // A row = wm*64 + mi*16 + r16, k = quad*8.. ; B row = wn*64 + ni*16 + r16
  const unsigned char* aRd = smem + (wm << 12) + (lane << 4);
  const unsigned char* bRd = smem + 8192 + (wn << 12) + (lane << 4);

  LOADS(0);
  CVTSTORE(0);           // vmcnt wait on loads(0) inserted here by compiler
  LOADS(1);

  for (int t = 0; t < NT; ++t) {
    BARRIER();                                  // buf[t&1] visible; old reads done
    if (t < NT - 1) CVTSTORE((t + 1) & 1);      // consumes in-flight loads(t+1)
    if (t < NT - 2) LOADS(t + 2);               // stays in flight across barrier

    const int cur = (t & 1) * BUFB;
    short8 af[4], bf[4];
#pragma unroll
    for (int ni = 0; ni < 4; ++ni)
      bf[ni] = *(const short8*)(bRd + cur + ni * 1024);
#pragma unroll
    for (int mi = 0; mi < 4; ++mi)
      af[mi] = *(const short8*)(aRd + cur + mi * 1024);
#pragma unroll
    for (int mi = 0; mi < 4; ++mi)
#pragma unroll
      for (int ni = 0; ni < 4; ++ni)
        acc[mi][ni] = __builtin_amdgcn_mfma_f32_16x16x32_bf16(
            af[mi], bf[ni], acc[mi][ni], 0, 0, 0);
  }

  // ---- Epilogue: gram[i,j] -> out[b, (i-j-450) mod 900]; 2 passes of 64 rows.
  __syncthreads();
  float* Ep = (float*)smem;                     // [64][132]
  const int dbase = it * 128 - jt * 128 - NPAD;

  for (int p = 0; p < 2; ++p) {
    if (wm == p) {
#pragma unroll
      for (int mi = 0; mi < 4; ++mi)
#pragma unroll
        for (int ni = 0; ni < 4; ++ni)
#pragma unroll
          for (int rr = 0; rr < 4; ++rr) {
            const int lr = mi * 16 + quad * 4 + rr;   // tile row p*64 + lr
            const int c  = wn * 64 + ni * 16 + r16;   // tile col
            Ep[lr * 132 + c] = acc[mi][ni][rr];
          }
    }
    __syncthreads();
    if (tid < 191) {
      const int d = tid - 127;                  // lr - c in [-127, 63]
      int k0 = d > 0 ? d : 0;
      int k1 = 128 + d; if (k1 > 64) k1 = 64;
      float s = 0.0f;
      for (int k = k0; k < k1; ++k) s += Ep[k * 132 + (k - d)];
      int dg = dbase + p * 64 + d;              // in (-1474, 574)
      int sidx = dg % W_DIM;
      if (sidx < 0) sidx += W_DIM;
      atomicAdd(&out[b * W_DIM + sidx], s);
    }
    __syncthreads();
  }
}

extern "C" void kernel_launch(void* const* d_in, const int* in_sizes, int n_in,
                              void* d_out, int out_size, void* d_ws, size_t ws_size,
                              hipStream_t stream) {
  const float* x1 = (const float*)d_in[0];
  const float* x2 = (const float*)d_in[1];
  float* out = (float*)d_out;

  hipMemsetAsync(d_out, 0, (size_t)out_size * sizeof(float), stream);
  fused_gram_band<<<dim3(1024), 256, 0, stream>>>(x1, x2, out);
}

// Round 6
// 201.195 us; speedup vs baseline: 2.7889x; 2.7889x over previous
//
#include <hip/hip_runtime.h>
#include <stdint.h>

typedef __attribute__((ext_vector_type(8))) short short8;
typedef __attribute__((ext_vector_type(8))) unsigned short ushort8;
typedef __attribute__((ext_vector_type(4))) float floatx4;

#define W_DIM 900
#define NPAD  450
#define TM    256
#define TN    128

__device__ __forceinline__ unsigned short f2bf(float f) {
  // round-half-up: bias ~2^-17 relative, negligible over 921600-term sums
  unsigned int u = __builtin_bit_cast(unsigned int, f);
  return (unsigned short)((u + 0x8000u) >> 16);
}

// ---------------------------------------------------------------------------
// Fused: fp32 inputs -> bf16 staged tiles -> gram GEMM -> circular-band reduce.
// out[b,s] = sum_{i-j-450 = s (mod 900)} <x1_i, x2_j>  (D = H*C = 1024)
//
// Round-6 = round-4/5 resubmitted (two container infra failures; kernel has
// never executed): round-0 structure (verified 73 us dispatch) +
// identity-slot LDS layout (verified in r3: bank conflicts 7.05M -> 0.38M).
//
// LDS image per k-tile: A = 16 subtiles, B = 8 subtiles of (16 rows x 32 k)
// bf16 = 1024 B each. Chunk (r16 = row&15, k8 = k>>3) lives at byte
// subtile*1024 + (k8*16 + r16)*16. MFMA frag lane L needs row L&15, k-chunk
// L>>4 -> slot == L, so ds_read_b128 = base + L*16 (conflict-free); the
// staging map uses the same (r16 = lane&15, k8 = lane>>4) assignment, so
// ds_write_b128 = base + lane*16 (conflict-free). Global byte set per wave
// is unchanged vs r0 (16 rows x 128 B), only lane->chunk assignment differs.
//
// Tile 256x128, BK=32. Grid: 512 blocks, x = jt*64 + it*16 + b so x%8 = b%8
// -> all blocks of one batch share an XCD (L2 tile reuse).
// 4 waves; wave (wm,wn) computes 128x64 via 8x4 frags of mfma 16x16x32_bf16.
// Pipeline: global loads for kt+1 issued after 2nd barrier, in flight across
// MFMA(kt) + next barrier; CVTSTORE(kt+1) vmcnt-waits them next iteration.
// ---------------------------------------------------------------------------
__global__ __launch_bounds__(256, 2)
void fused_gram_band(const float* __restrict__ X1, const float* __restrict__ X2,
                     float* __restrict__ out) {
  const int x  = blockIdx.x;
  const int b  = x & 15;
  const int it = (x >> 4) & 3;         // A tile: rows it*256..
  const int jt = x >> 6;               // B tile: rows jt*128..

  __shared__ __align__(16) unsigned char smem[64 * 132 * 4];  // 33792 B
  // staging: A image [16 subtiles] at 0..16383, B image [8 subtiles] at
  // 16384..24575; epilogue Ep[64][132] f32 aliases all of it.

  const int tid  = threadIdx.x;
  const int lane = tid & 63;
  const int warp = tid >> 6;
  const int wm   = warp >> 1;
  const int wn   = warp & 1;
  const int r16  = lane & 15;
  const int quad = lane >> 4;          // k-chunk 0..3 (8 floats each)

  // ---- staging rows: warp stages A subtiles warp*4+s (s=0..3), B subtiles
  // warp*2+s (s=0..1); within a subtile this thread owns (row r16, chunk quad).
  int arow[4], brow[2];
  bool aok[4], bok[2];
#pragma unroll
  for (int s = 0; s < 4; ++s) {
    arow[s] = it * TM + (warp * 4 + s) * 16 + r16;
    aok[s]  = arow[s] < W_DIM;         // padded rows (>=900) stay zero
  }
#pragma unroll
  for (int s = 0; s < 2; ++s) {
    brow[s] = jt * TN + (warp * 2 + s) * 16 + r16;
    bok[s]  = brow[s] < W_DIM;
  }

  const size_t bbase = (size_t)b * 4 * W_DIM * 256;
  const int kcol = quad * 8;

  float4 va[4][2], vb[2][2];
  const float4 fz = make_float4(0.f, 0.f, 0.f, 0.f);

#define LOAD_SLAB(kt)                                                          \
  {                                                                            \
    const size_t koff = bbase + (size_t)((kt) >> 3) * (W_DIM * 256) +          \
                        ((kt) & 7) * 32 + kcol;                                \
    _Pragma("unroll")                                                          \
    for (int s = 0; s < 4; ++s) {                                              \
      va[s][0] = fz; va[s][1] = fz;                                            \
      if (aok[s]) {                                                            \
        const float* p = X1 + koff + (size_t)arow[s] * 256;                    \
        va[s][0] = *(const float4*)p;                                          \
        va[s][1] = *(const float4*)(p + 4);                                    \
      }                                                                        \
    }                                                                          \
    _Pragma("unroll")                                                          \
    for (int s = 0; s < 2; ++s) {                                              \
      vb[s][0] = fz; vb[s][1] = fz;                                            \
      if (bok[s]) {                                                            \
        const float* p = X2 + koff + (size_t)brow[s] * 256;                    \
        vb[s][0] = *(const float4*)p;                                          \
        vb[s][1] = *(const float4*)(p + 4);                                    \
      }                                                                        \
    }                                                                          \
  }

  floatx4 acc[8][4];
#pragma unroll
  for (int i = 0; i < 8; ++i)
#pragma unroll
    for (int j = 0; j < 4; ++j) acc[i][j] = (floatx4)0.0f;

  // staging write bases (identity slots): subtile base + lane*16
  unsigned char* aWr = smem + warp * 4096 + (lane << 4);           // +s*1024
  unsigned char* bWr = smem + 16384 + warp * 2048 + (lane << 4);   // +s*1024

  // frag read bases (identity slots): wave's subtile base + lane*16
  const unsigned char* aRd = smem + wm * 8192 + (lane << 4);          // +mi*1024
  const unsigned char* bRd = smem + 16384 + wn * 4096 + (lane << 4);  // +ni*1024

  LOAD_SLAB(0);

  for (int kt = 0; kt < 32; ++kt) {
    __syncthreads();                   // frag reads of kt-1 done before overwrite
    // convert + write slab kt (compiler inserts vmcnt wait on va/vb here)
#pragma unroll
    for (int s = 0; s < 4; ++s) {
      ushort8 o;
      o[0] = f2bf(va[s][0].x); o[1] = f2bf(va[s][0].y);
      o[2] = f2bf(va[s][0].z); o[3] = f2bf(va[s][0].w);
      o[4] = f2bf(va[s][1].x); o[5] = f2bf(va[s][1].y);
      o[6] = f2bf(va[s][1].z); o[7] = f2bf(va[s][1].w);
      *(ushort8*)(aWr + s * 1024) = o;
    }
#pragma unroll
    for (int s = 0; s < 2; ++s) {
      ushort8 o;
      o[0] = f2bf(vb[s][0].x); o[1] = f2bf(vb[s][0].y);
      o[2] = f2bf(vb[s][0].z); o[3] = f2bf(vb[s][0].w);
      o[4] = f2bf(vb[s][1].x); o[5] = f2bf(vb[s][1].y);
      o[6] = f2bf(vb[s][1].z); o[7] = f2bf(vb[s][1].w);
      *(ushort8*)(bWr + s * 1024) = o;
    }
    __syncthreads();                   // writes visible

    if (kt < 31) LOAD_SLAB(kt + 1);    // in flight across MFMA + next barrier

    short8 af[8], bf[4];
#pragma unroll
    for (int mi = 0; mi < 8; ++mi)
      af[mi] = *(const short8*)(aRd + mi * 1024);
#pragma unroll
    for (int ni = 0; ni < 4; ++ni)
      bf[ni] = *(const short8*)(bRd + ni * 1024);
#pragma unroll
    for (int mi = 0; mi < 8; ++mi)
#pragma unroll
      for (int ni = 0; ni < 4; ++ni)
        acc[mi][ni] = __builtin_amdgcn_mfma_f32_16x16x32_bf16(
            af[mi], bf[ni], acc[mi][ni], 0, 0, 0);
  }

  // ---- Epilogue: gram[i,j] -> out[b, (i-j-450) mod 900]; 4 passes of 64 rows.
  __syncthreads();
  float* Ep = (float*)smem;            // [64][132]
  const int dbase = it * TM - jt * TN - NPAD;

  for (int p = 0; p < 4; ++p) {
    if (wm == (p >> 1)) {
      const int mib = (p & 1) * 4;
#pragma unroll
      for (int mo = 0; mo < 4; ++mo)
#pragma unroll
        for (int ni = 0; ni < 4; ++ni)
#pragma unroll
          for (int rr = 0; rr < 4; ++rr) {
            const int lr = mo * 16 + quad * 4 + rr;       // tile row p*64 + lr
            const int c  = wn * 64 + ni * 16 + r16;       // tile col
            Ep[lr * 132 + c] = acc[mib + mo][ni][rr];
          }
    }
    __syncthreads();
    if (tid < 191) {
      const int d = tid - 127;         // lr - c in [-127, 63]
      int k0 = d > 0 ? d : 0;
      int k1 = 128 + d; if (k1 > 64) k1 = 64;
      float s = 0.0f;
      for (int k = k0; k < k1; ++k) s += Ep[k * 132 + (k - d)];
      int dg = dbase + p * 64 + d;     // in (-1800, 1800)
      int sidx = dg % W_DIM;
      if (sidx < 0) sidx += W_DIM;
      atomicAdd(&out[b * W_DIM + sidx], s);
    }
    __syncthreads();
  }
}

extern "C" void kernel_launch(void* const* d_in, const int* in_sizes, int n_in,
                              void* d_out, int out_size, void* d_ws, size_t ws_size,
                              hipStream_t stream) {
  const float* x1 = (const float*)d_in[0];
  const float* x2 = (const float*)d_in[1];
  float* out = (float*)d_out;

  hipMemsetAsync(d_out, 0, (size_t)out_size * sizeof(float), stream);
  fused_gram_band<<<dim3(512), 256, 0, stream>>>(x1, x2, out);
}

// Round 7
// 169.229 us; speedup vs baseline: 3.3157x; 1.1889x over previous
//
#include <hip/hip_runtime.h>
#include <stdint.h>

typedef __attribute__((ext_vector_type(8))) short short8;
typedef __attribute__((ext_vector_type(8))) unsigned short ushort8;
typedef __attribute__((ext_vector_type(4))) float floatx4;

#define W_DIM 900
#define NPAD  450
#define TM    256
#define TN    128
#define NT    32
#define BUFB  24576        // one LDS buffer: A 16 KB + B 8 KB

__device__ __forceinline__ unsigned short f2bf(float f) {
  // round-half-up: bias ~2^-17 relative, negligible over 921600-term sums
  unsigned int u = __builtin_bit_cast(unsigned int, f);
  return (unsigned short)((u + 0x8000u) >> 16);
}

// Raw barrier: drain own LDS ops, then workgroup barrier. Global loads stay
// in flight across it (__syncthreads would add vmcnt(0) and kill prefetch).
#define BARRIER() do { asm volatile("s_waitcnt lgkmcnt(0)" ::: "memory"); \
                       __builtin_amdgcn_s_barrier(); } while (0)

// ---------------------------------------------------------------------------
// Fused: fp32 inputs -> bf16 staged tiles -> gram GEMM -> circular-band reduce.
// out[b,s] = sum_{i-j-450 = s (mod 900)} <x1_i, x2_j>  (D = H*C = 1024)
//
// Round-7: r0 global-load map (fully coalesced: 4 lanes x 32B = 128B/row,
// r6's map halved line coverage -> +47us VMEM) + swizzled-slot LDS layout.
// Slot s = k8*16 + r16 for chunk (r16=row&15, k8=k>>3); stored at position
// p = s ^ ((s>>3)&6)  (XOR k8 bits into bank-group bits). Under 8- or 16-lane
// LDS phasing, both the staging writes (lane -> row lane>>2, k8 lane&3) and
// the frag reads (lane -> s=lane) map p mod 8 bijectively per lane group ->
// zero bank conflicts on ds_write_b128 AND ds_read_b128 (r6 verified the
// conflict counter collapse for the read side; write side is the new swizzle).
//
// Pipeline (new vs r0): LDS double-buffered (2 x 24 KB), ONE lgkm-only
// barrier per k-tile. iter t: BARRIER (buf[t&1] visible; last iter's reads
// drained); frag-read buf[t&1]; CVTSTORE(t+1)->buf[(t+1)&1] (vmcnt-waits
// loads(t+1)); LOADS(t+2) issued, in flight across next barrier; 32 MFMA.
// MFMA(t) overlaps convert(t+1) within the wave; half the barriers of r0.
//
// Tile 256x128, BK=32. Grid 512, x = jt*64 + it*16 + b so x%8 = b%8 (XCD
// batch affinity). 4 waves; wave (wm,wn) = 128x64 via 8x4 frags 16x16x32bf16.
// ---------------------------------------------------------------------------
__global__ __launch_bounds__(256, 2)
void fused_gram_band(const float* __restrict__ X1, const float* __restrict__ X2,
                     float* __restrict__ out) {
  const int x  = blockIdx.x;
  const int b  = x & 15;
  const int it = (x >> 4) & 3;         // A tile: rows it*256..
  const int jt = x >> 6;               // B tile: rows jt*128..

  __shared__ __align__(16) unsigned char smem[2 * BUFB];   // 49152 B
  // per buffer: A = 16 subtiles @ 0.., B = 8 subtiles @ 16384..; subtile =
  // (16 rows x 32 k) bf16 = 1024 B. Epilogue Ep[64][132] f32 (33792 B) aliases.

  const int tid  = threadIdx.x;
  const int lane = tid & 63;
  const int warp = tid >> 6;
  const int wm   = warp >> 1;
  const int wn   = warp & 1;
  const int r16  = lane & 15;
  const int quad = lane >> 4;

  // ---- staging lane map (r0, coalesced): row-sub q = lane>>2, k8 chunk c.
  const int q  = lane >> 2;
  const int c  = lane & 3;
  const int c8 = c << 3;               // element offset within 32-elem k-tile

  // swizzled slot positions: p = s ^ ((s>>3)&6)
  const int pw = (((c << 4) | q) ^ (c << 1)) << 4;       // write: s=(c<<4)|q
  const int pr = (lane ^ ((lane >> 3) & 6)) << 4;        // read:  s=lane

  int arow[4], brow[2];
  bool aok[4], bok[2];
#pragma unroll
  for (int s = 0; s < 4; ++s) {
    arow[s] = it * TM + (warp * 4 + s) * 16 + q;
    aok[s]  = arow[s] < W_DIM;         // padded rows (>=900) stay zero
  }
#pragma unroll
  for (int s = 0; s < 2; ++s) {
    brow[s] = jt * TN + (warp * 2 + s) * 16 + q;
    bok[s]  = brow[s] < W_DIM;
  }

  const size_t bbase = (size_t)b * 4 * W_DIM * 256;

  float4 va[4][2], vb[2][2];
  const float4 fz = make_float4(0.f, 0.f, 0.f, 0.f);

#define LOAD_SLAB(kt)                                                          \
  {                                                                            \
    const size_t koff = bbase + (size_t)((kt) >> 3) * (W_DIM * 256) +          \
                        ((kt) & 7) * 32 + c8;                                  \
    _Pragma("unroll")                                                          \
    for (int s = 0; s < 4; ++s) {                                              \
      va[s][0] = fz; va[s][1] = fz;                                            \
      if (aok[s]) {                                                            \
        const float* p = X1 + koff + (size_t)arow[s] * 256;                    \
        va[s][0] = *(const float4*)p;                                          \
        va[s][1] = *(const float4*)(p + 4);                                    \
      }                                                                        \
    }                                                                          \
    _Pragma("unroll")                                                          \
    for (int s = 0; s < 2; ++s) {                                              \
      vb[s][0] = fz; vb[s][1] = fz;                                            \
      if (bok[s]) {                                                            \
        const float* p = X2 + koff + (size_t)brow[s] * 256;                    \
        vb[s][0] = *(const float4*)p;                                          \
        vb[s][1] = *(const float4*)(p + 4);                                    \
      }                                                                        \
    }                                                                          \
  }

  // staging write bases (swizzled slots): subtile base + pw
  unsigned char* aWr = smem + warp * 4096 + pw;            // + s*1024 (+buf)
  unsigned char* bWr = smem + 16384 + warp * 2048 + pw;    // + s*1024 (+buf)

#define CVTSTORE(bo_)                                                          \
  {                                                                            \
    _Pragma("unroll")                                                          \
    for (int s = 0; s < 4; ++s) {                                              \
      ushort8 o;                                                               \
      o[0] = f2bf(va[s][0].x); o[1] = f2bf(va[s][0].y);                        \
      o[2] = f2bf(va[s][0].z); o[3] = f2bf(va[s][0].w);                        \
      o[4] = f2bf(va[s][1].x); o[5] = f2bf(va[s][1].y);                        \
      o[6] = f2bf(va[s][1].z); o[7] = f2bf(va[s][1].w);                        \
      *(ushort8*)(aWr + (bo_) + s * 1024) = o;                                 \
    }                                                                          \
    _Pragma("unroll")                                                          \
    for (int s = 0; s < 2; ++s) {                                              \
      ushort8 o;                                                               \
      o[0] = f2bf(vb[s][0].x); o[1] = f2bf(vb[s][0].y);                        \
      o[2] = f2bf(vb[s][0].z); o[3] = f2bf(vb[s][0].w);                        \
      o[4] = f2bf(vb[s][1].x); o[5] = f2bf(vb[s][1].y);                        \
      o[6] = f2bf(vb[s][1].z); o[7] = f2bf(vb[s][1].w);                        \
      *(ushort8*)(bWr + (bo_) + s * 1024) = o;                                 \
    }                                                                          \
  }

  floatx4 acc[8][4];
#pragma unroll
  for (int i = 0; i < 8; ++i)
#pragma unroll
    for (int j = 0; j < 4; ++j) acc[i][j] = (floatx4)0.0f;

  // frag read bases (swizzled slots): wave's subtile base + pr
  const unsigned char* aRd = smem + wm * 8192 + pr;           // + mi*1024 (+buf)
  const unsigned char* bRd = smem + 16384 + wn * 4096 + pr;   // + ni*1024 (+buf)

  LOAD_SLAB(0);
  CVTSTORE(0);           // vmcnt wait on loads(0) inserted here by compiler
  LOAD_SLAB(1);

  for (int t = 0; t < NT; ++t) {
    BARRIER();           // buf[t&1] stores visible; last iter's reads drained
    const int bo = (t & 1) * BUFB;

    short8 af[8], bf[4];
#pragma unroll
    for (int mi = 0; mi < 8; ++mi)
      af[mi] = *(const short8*)(aRd + bo + mi * 1024);
#pragma unroll
    for (int ni = 0; ni < 4; ++ni)
      bf[ni] = *(const short8*)(bRd + bo + ni * 1024);

    if (t < NT - 1) CVTSTORE((t + 1) & 1 ? BUFB : 0);  // consume loads(t+1)
    if (t < NT - 2) LOAD_SLAB(t + 2);                  // in flight over barrier

#pragma unroll
    for (int mi = 0; mi < 8; ++mi)
#pragma unroll
      for (int ni = 0; ni < 4; ++ni)
        acc[mi][ni] = __builtin_amdgcn_mfma_f32_16x16x32_bf16(
            af[mi], bf[ni], acc[mi][ni], 0, 0, 0);
  }

  // ---- Epilogue: gram[i,j] -> out[b, (i-j-450) mod 900]; 4 passes of 64 rows.
  __syncthreads();
  float* Ep = (float*)smem;            // [64][132]
  const int dbase = it * TM - jt * TN - NPAD;

  for (int p = 0; p < 4; ++p) {
    if (wm == (p >> 1)) {
      const int mib = (p & 1) * 4;
#pragma unroll
      for (int mo = 0; mo < 4; ++mo)
#pragma unroll
        for (int ni = 0; ni < 4; ++ni)
#pragma unroll
          for (int rr = 0; rr < 4; ++rr) {
            const int lr = mo * 16 + quad * 4 + rr;       // tile row p*64 + lr
            const int cc = wn * 64 + ni * 16 + r16;       // tile col
            Ep[lr * 132 + cc] = acc[mib + mo][ni][rr];
          }
    }
    __syncthreads();
    if (tid < 191) {
      const int d = tid - 127;         // lr - c in [-127, 63]
      int k0 = d > 0 ? d : 0;
      int k1 = 128 + d; if (k1 > 64) k1 = 64;
      float s = 0.0f;
      for (int k = k0; k < k1; ++k) s += Ep[k * 132 + (k - d)];
      int dg = dbase + p * 64 + d;     // in (-1800, 1800)
      int sidx = dg % W_DIM;
      if (sidx < 0) sidx += W_DIM;
      atomicAdd(&out[b * W_DIM + sidx], s);
    }
    __syncthreads();
  }
}

extern "C" void kernel_launch(void* const* d_in, const int* in_sizes, int n_in,
                              void* d_out, int out_size, void* d_ws, size_t ws_size,
                              hipStream_t stream) {
  const float* x1 = (const float*)d_in[0];
  const float* x2 = (const float*)d_in[1];
  float* out = (float*)d_out;

  hipMemsetAsync(d_out, 0, (size_t)out_size * sizeof(float), stream);
  fused_gram_band<<<dim3(512), 256, 0, stream>>>(x1, x2, out);
}

// Round 8
// 162.411 us; speedup vs baseline: 3.4549x; 1.0420x over previous
//
#include <hip/hip_runtime.h>
#include <stdint.h>

typedef __attribute__((ext_vector_type(8))) short short8;
typedef __attribute__((ext_vector_type(8))) unsigned short ushort8;
typedef __attribute__((ext_vector_type(4))) float floatx4;

#define W_DIM 900
#define NPAD  450
#define TM    256
#define TN    128
#define NT    32
#define BUFB  24576        // one LDS buffer: A 16 KB + B 8 KB

__device__ __forceinline__ unsigned short f2bf(float f) {
  // round-half-up: bias ~2^-17 relative, negligible over 921600-term sums
  unsigned int u = __builtin_bit_cast(unsigned int, f);
  return (unsigned short)((u + 0x8000u) >> 16);
}

// Raw barrier: drain own LDS ops, then workgroup barrier. Global loads stay
// in flight across it (__syncthreads would add vmcnt(0) and kill prefetch).
#define BARRIER() do { asm volatile("s_waitcnt lgkmcnt(0)" ::: "memory"); \
                       __builtin_amdgcn_s_barrier(); } while (0)

// ---------------------------------------------------------------------------
// Fused: fp32 inputs -> bf16 staged tiles -> gram GEMM -> circular-band reduce.
// out[b,s] = sum_{i-j-450 = s (mod 900)} <x1_i, x2_j>  (D = H*C = 1024)
//
// Round-8 = r7 loop (coalesced loads + swizzled-slot LDS, conflicts 0.38M,
// dbuf + 1 lgkm barrier/k-tile, 74.7us) + two fixes:
//  (a) epilogue band-sum unrolled x8 with 4 independent partials: the old
//      runtime-bounded serial `s += Ep[k]` chain exposed ~120cyc ds_read
//      latency per element (~13us over 4 passes); unrolling pipelines it.
//  (b) no conditional zero-fill in the hot loop: OOB tile rows (>=900) clamp
//      their SOURCE POINTER to row 899 (in-bounds garbage); the epilogue
//      k-range is clamped so gram entries with row>=900 or col>=900 are
//      never summed (k < 900-it*256-p*64 and k < 900+d-jt*128). Kills the
//      per-k-tile cndmask/exec-mask + 24 pre-zero v_movs.
//
// LDS slot swizzle p = s ^ ((s>>3)&6): staging writes (lane -> row lane>>2,
// chunk lane&3) and frag reads (lane -> slot lane) both map bank-group
// bijectively per 8-lane group -> conflict-free b128 both ways.
//
// Tile 256x128, BK=32. Grid 512, x = jt*64 + it*16 + b so x%8 = b%8 (XCD
// batch affinity). 4 waves; wave (wm,wn) = 128x64 via 8x4 frags 16x16x32bf16.
// Pipeline: iter t: BARRIER; frag-read buf[t&1]; CVTSTORE(t+1)->buf[~t]
// (vmcnt-waits loads(t+1)); issue LOADS(t+2); 32 MFMA.
// ---------------------------------------------------------------------------
__global__ __launch_bounds__(256, 2)
void fused_gram_band(const float* __restrict__ X1, const float* __restrict__ X2,
                     float* __restrict__ out) {
  const int x  = blockIdx.x;
  const int b  = x & 15;
  const int it = (x >> 4) & 3;         // A tile: rows it*256..
  const int jt = x >> 6;               // B tile: rows jt*128..

  __shared__ __align__(16) unsigned char smem[2 * BUFB];   // 49152 B
  // per buffer: A = 16 subtiles @ 0.., B = 8 subtiles @ 16384..; subtile =
  // (16 rows x 32 k) bf16 = 1024 B. Epilogue Ep[64][132] f32 (33792 B) aliases.

  const int tid  = threadIdx.x;
  const int lane = tid & 63;
  const int warp = tid >> 6;
  const int wm   = warp >> 1;
  const int wn   = warp & 1;
  const int r16  = lane & 15;
  const int quad = lane >> 4;

  // ---- staging lane map (coalesced): row-sub q = lane>>2, k8 chunk c.
  const int q  = lane >> 2;
  const int c  = lane & 3;
  const int c8 = c << 3;               // element offset within 32-elem k-tile

  // swizzled slot positions: p = s ^ ((s>>3)&6)
  const int pw = (((c << 4) | q) ^ (c << 1)) << 4;       // write: s=(c<<4)|q
  const int pr = (lane ^ ((lane >> 3) & 6)) << 4;        // read:  s=lane

  const size_t bbase = (size_t)b * 4 * W_DIM * 256;

  // row pointers, clamped to row 899 (garbage rows excluded in epilogue)
  const float* pA[4];
  const float* pB[2];
#pragma unroll
  for (int s = 0; s < 4; ++s) {
    int r = it * TM + (warp * 4 + s) * 16 + q;
    if (r > W_DIM - 1) r = W_DIM - 1;
    pA[s] = X1 + bbase + (size_t)r * 256 + c8;
  }
#pragma unroll
  for (int s = 0; s < 2; ++s) {
    int r = jt * TN + (warp * 2 + s) * 16 + q;
    if (r > W_DIM - 1) r = W_DIM - 1;
    pB[s] = X2 + bbase + (size_t)r * 256 + c8;
  }

  float4 va[4][2], vb[2][2];

#define LOAD_SLAB(kt)                                                          \
  {                                                                            \
    const size_t koff = (size_t)((kt) >> 3) * (W_DIM * 256) +                  \
                        ((kt) & 7) * 32;                                       \
    _Pragma("unroll")                                                          \
    for (int s = 0; s < 4; ++s) {                                              \
      va[s][0] = *(const float4*)(pA[s] + koff);                               \
      va[s][1] = *(const float4*)(pA[s] + koff + 4);                           \
    }                                                                          \
    _Pragma("unroll")                                                          \
    for (int s = 0; s < 2; ++s) {                                              \
      vb[s][0] = *(const float4*)(pB[s] + koff);                               \
      vb[s][1] = *(const float4*)(pB[s] + koff + 4);                           \
    }                                                                          \
  }

  // staging write bases (swizzled slots): subtile base + pw
  unsigned char* aWr = smem + warp * 4096 + pw;            // + s*1024 (+buf)
  unsigned char* bWr = smem + 16384 + warp * 2048 + pw;    // + s*1024 (+buf)

#define CVTSTORE(bo_)                                                          \
  {                                                                            \
    _Pragma("unroll")                                                          \
    for (int s = 0; s < 4; ++s) {                                              \
      ushort8 o;                                                               \
      o[0] = f2bf(va[s][0].x); o[1] = f2bf(va[s][0].y);                        \
      o[2] = f2bf(va[s][0].z); o[3] = f2bf(va[s][0].w);                        \
      o[4] = f2bf(va[s][1].x); o[5] = f2bf(va[s][1].y);                        \
      o[6] = f2bf(va[s][1].z); o[7] = f2bf(va[s][1].w);                        \
      *(ushort8*)(aWr + (bo_) + s * 1024) = o;                                 \
    }                                                                          \
    _Pragma("unroll")                                                          \
    for (int s = 0; s < 2; ++s) {                                              \
      ushort8 o;                                                               \
      o[0] = f2bf(vb[s][0].x); o[1] = f2bf(vb[s][0].y);                        \
      o[2] = f2bf(vb[s][0].z); o[3] = f2bf(vb[s][0].w);                        \
      o[4] = f2bf(vb[s][1].x); o[5] = f2bf(vb[s][1].y);                        \
      o[6] = f2bf(vb[s][1].z); o[7] = f2bf(vb[s][1].w);                        \
      *(ushort8*)(bWr + (bo_) + s * 1024) = o;                                 \
    }                                                                          \
  }

  floatx4 acc[8][4];
#pragma unroll
  for (int i = 0; i < 8; ++i)
#pragma unroll
    for (int j = 0; j < 4; ++j) acc[i][j] = (floatx4)0.0f;

  // frag read bases (swizzled slots): wave's subtile base + pr
  const unsigned char* aRd = smem + wm * 8192 + pr;           // + mi*1024 (+buf)
  const unsigned char* bRd = smem + 16384 + wn * 4096 + pr;   // + ni*1024 (+buf)

  LOAD_SLAB(0);
  CVTSTORE(0);           // vmcnt wait on loads(0) inserted here by compiler
  LOAD_SLAB(1);

  for (int t = 0; t < NT; ++t) {
    BARRIER();           // buf[t&1] stores visible; last iter's reads drained
    const int bo = (t & 1) * BUFB;

    short8 af[8], bf[4];
#pragma unroll
    for (int mi = 0; mi < 8; ++mi)
      af[mi] = *(const short8*)(aRd + bo + mi * 1024);
#pragma unroll
    for (int ni = 0; ni < 4; ++ni)
      bf[ni] = *(const short8*)(bRd + bo + ni * 1024);

    if (t < NT - 1) CVTSTORE((t + 1) & 1 ? BUFB : 0);  // consume loads(t+1)
    if (t < NT - 2) LOAD_SLAB(t + 2);                  // in flight over barrier

#pragma unroll
    for (int mi = 0; mi < 8; ++mi)
#pragma unroll
      for (int ni = 0; ni < 4; ++ni)
        acc[mi][ni] = __builtin_amdgcn_mfma_f32_16x16x32_bf16(
            af[mi], bf[ni], acc[mi][ni], 0, 0, 0);
  }

  // ---- Epilogue: gram[i,j] -> out[b, (i-j-450) mod 900]; 4 passes of 64 rows.
  __syncthreads();
  float* Ep = (float*)smem;            // [64][132]
  const int dbase = it * TM - jt * TN - NPAD;

  for (int p = 0; p < 4; ++p) {
    if (wm == (p >> 1)) {
      const int mib = (p & 1) * 4;
#pragma unroll
      for (int mo = 0; mo < 4; ++mo)
#pragma unroll
        for (int ni = 0; ni < 4; ++ni)
#pragma unroll
          for (int rr = 0; rr < 4; ++rr) {
            const int lr = mo * 16 + quad * 4 + rr;       // tile row p*64 + lr
            const int cc = wn * 64 + ni * 16 + r16;       // tile col
            Ep[lr * 132 + cc] = acc[mib + mo][ni][rr];
          }
    }
    __syncthreads();
    if (tid < 191) {
      const int d = tid - 127;         // lr - c in [-127, 63]
      int k0 = d > 0 ? d : 0;
      int k1 = 128 + d; if (k1 > 64) k1 = 64;
      // validity clamps (replaces hot-loop zero-fill): row it*256+p*64+k<900,
      // col jt*128+k-d<900
      {
        int kr = W_DIM - it * TM - p * 64;      // k < kr
        int kc = W_DIM + d - jt * TN;           // k < kc
        if (k1 > kr) k1 = kr;
        if (k1 > kc) k1 = kc;
      }
      if (k1 > k0) {
        float s0 = 0.f, s1 = 0.f, s2 = 0.f, s3 = 0.f;
        int k = k0;
        for (; k + 8 <= k1; k += 8) {
          s0 += Ep[(k + 0) * 133 - d];
          s1 += Ep[(k + 1) * 133 - d];
          s2 += Ep[(k + 2) * 133 - d];
          s3 += Ep[(k + 3) * 133 - d];
          s0 += Ep[(k + 4) * 133 - d];
          s1 += Ep[(k + 5) * 133 - d];
          s2 += Ep[(k + 6) * 133 - d];
          s3 += Ep[(k + 7) * 133 - d];
        }
        for (; k < k1; ++k) s0 += Ep[k * 133 - d];
        float s = (s0 + s1) + (s2 + s3);
        int dg = dbase + p * 64 + d;            // in (-1800, 1800)
        int sidx = dg % W_DIM;
        if (sidx < 0) sidx += W_DIM;
        atomicAdd(&out[b * W_DIM + sidx], s);
      }
    }
    __syncthreads();
  }
}

extern "C" void kernel_launch(void* const* d_in, const int* in_sizes, int n_in,
                              void* d_out, int out_size, void* d_ws, size_t ws_size,
                              hipStream_t stream) {
  const float* x1 = (const float*)d_in[0];
  const float* x2 = (const float*)d_in[1];
  float* out = (float*)d_out;

  hipMemsetAsync(d_out, 0, (size_t)out_size * sizeof(float), stream);
  fused_gram_band<<<dim3(512), 256, 0, stream>>>(x1, x2, out);
}